// Round 24
// baseline (78.336 us; speedup 1.0000x reference)
//
#include <hip/hip_runtime.h>

#define LSEQ 2048
#define EMB  512
#define NH   8
#define HD   64
#define NBATCH 4
// 1/sqrt(512) * log2(e): folded into Wq at prep; softmax runs in exp2 domain
#define QSCALE (0.044194173824159216f * 1.4426950408889634f)

using short8  = __attribute__((ext_vector_type(8))) short;
using short4v = __attribute__((ext_vector_type(4))) short;
using f32x4   = __attribute__((ext_vector_type(4))) float;

__device__ __forceinline__ short bf16r(float f) {
  union { float f; unsigned u; } x; x.f = f;
  unsigned r = x.u + 0x7FFFu + ((x.u >> 16) & 1u);
  return (short)(r >> 16);
}

__device__ __forceinline__ float exp2v(float x) {
  float r;
  asm("v_exp_f32 %0, %1" : "=v"(r) : "v"(x));   // D = 2^S0
  return r;
}

// pack two f32 -> two bf16 in one dword (lo -> [15:0], hi -> [31:16]); RNE
__device__ __forceinline__ unsigned cvtpk(float lo, float hi) {
  unsigned r;
  asm("v_cvt_pk_bf16_f32 %0, %1, %2" : "=v"(r) : "v"(lo), "v"(hi));
  return r;
}

// async global->LDS, 16B per lane; lds dest is wave-uniform (HW adds lane*16)
__device__ __forceinline__ void stage16(const void* g, void* l) {
  __builtin_amdgcn_global_load_lds(
      (const __attribute__((address_space(1))) unsigned int*)g,
      (__attribute__((address_space(3))) unsigned int*)l, 16, 0, 0);
}

__device__ __forceinline__ short8 cvt8(const float* __restrict__ p) {
  float4 a = ((const float4*)p)[0];
  float4 b = ((const float4*)p)[1];
  short8 r;
  r[0]=bf16r(a.x); r[1]=bf16r(a.y); r[2]=bf16r(a.z); r[3]=bf16r(a.w);
  r[4]=bf16r(b.x); r[5]=bf16r(b.y); r[6]=bf16r(b.z); r[7]=bf16r(b.w);
  return r;
}

__device__ __forceinline__ short8 ld8(const short* __restrict__ p) {
  return *(const short8*)p;
}

// ---- prep (16 blocks): mask compaction (0..3) | Wq*QSCALE,Wk,Wv->bf16 (4..15)
__global__ __launch_bounds__(256) void prep_kernel(
    const int* __restrict__ mask, float* __restrict__ fbias,
    int* __restrict__ kidx, int* __restrict__ meta,
    const float* __restrict__ Wq, const float* __restrict__ Wk,
    const float* __restrict__ Wv, short* __restrict__ Wqb,
    short* __restrict__ Wkb, short* __restrict__ Wvb) {
  __shared__ int ssum[256];
  int b = blockIdx.x;
  int tid = threadIdx.x;
  if (b < 4) {
    int n = b;
    int base = n * LSEQ;
    int loc[8], c = 0;
#pragma unroll
    for (int j = 0; j < 8; j++) { loc[j] = mask[base + tid * 8 + j] != 0; c += loc[j]; }
    ssum[tid] = c;
    __syncthreads();
    for (int off = 1; off < 256; off <<= 1) {
      int v = (tid >= off) ? ssum[tid - off] : 0;
      __syncthreads();
      ssum[tid] += v;
      __syncthreads();
    }
    int total = ssum[255];
    int excl = ssum[tid] - c;
    int qz = (total == 0);
#pragma unroll
    for (int j = 0; j < 8; j++) {
      int i = tid * 8 + j;
      kidx[base + i] = qz ? i : 0;
      fbias[base + i] = (qz || i < total) ? 0.f : -1e30f;
    }
    __syncthreads();
    if (!qz) {
      int pos = excl;
#pragma unroll
      for (int j = 0; j < 8; j++)
        if (loc[j]) { kidx[base + pos] = tid * 8 + j; pos++; }
    }
    if (tid == 0) {
      meta[n] = qz ? (LSEQ / 64) : ((total + 63) >> 6);
      meta[4 + n] = qz;
    }
  } else {
    int t = (b - 4) >> 2;                      // 0=Wq 1=Wk 2=Wv
    int i = ((b - 4) & 3) * 256 + tid;         // 1024 float4 per 64x64 W
    const float* W = (t == 0) ? Wq : (t == 1) ? Wk : Wv;
    short* O = (t == 0) ? Wqb : (t == 1) ? Wkb : Wvb;
    float sc = (t == 0) ? QSCALE : 1.f;
    float4 v = ((const float4*)W)[i];
    short4v r;
    r[0]=bf16r(v.x*sc); r[1]=bf16r(v.y*sc); r[2]=bf16r(v.z*sc); r[3]=bf16r(v.w*sc);
    ((short4v*)O)[i] = r;
  }
}

// --------------------------------------------- K/V projections (Q is in attn)
// K/V rows gathered through kidx (compacted keys), written up to the
// EVEN-rounded tile count ((meta+1)&~1)*64 rows; pad rows hold deterministic
// finite data (kidx=0, fbias=-1e30), never stale memory.
__global__ __launch_bounds__(256) void proj_kernel(
    const float* __restrict__ keys, const float* __restrict__ values,
    const short* __restrict__ Wkb, const short* __restrict__ Wvb,
    const int* __restrict__ kidx, const int* __restrict__ meta,
    short* __restrict__ Kp, short* __restrict__ Vt) {
  __shared__ short tile[64][72];                 // +8 pad
  int t = blockIdx.y + 1;                        // 1=K, 2=V
  const float* x = (t == 1) ? keys : values;
  const short* W = (t == 1) ? Wkb  : Wvb;
  int idx = blockIdx.x;
  int lt = idx & 31, h = (idx >> 5) & 7, n = idx >> 8;
  int tid = threadIdx.x, lane = tid & 63, w = tid >> 6;
  int row16 = lane & 15, g = lane >> 4;
  int lbase = lt * 64 + w * 16;

  if (lbase >= ((meta[n] + 1) & ~1) * 64) return;   // pad to even 64-tiles
  int gidx = kidx[n * LSEQ + lbase + row16];
  const float* xr = x + ((size_t)(n * LSEQ + gidx)) * EMB + h * HD + g * 8;
  short8 a0 = cvt8(xr);
  short8 a1 = cvt8(xr + 32);

  f32x4 acc[4];
#pragma unroll
  for (int et = 0; et < 4; et++) acc[et] = (f32x4){0.f, 0.f, 0.f, 0.f};
#pragma unroll
  for (int et = 0; et < 4; et++) {
    const short* wr = W + (size_t)(et * 16 + row16) * HD + g * 8;
    short8 b0 = ld8(wr);
    short8 b1 = ld8(wr + 32);
    acc[et] = __builtin_amdgcn_mfma_f32_16x16x32_bf16(a0, b0, acc[et], 0, 0, 0);
    acc[et] = __builtin_amdgcn_mfma_f32_16x16x32_bf16(a1, b1, acc[et], 0, 0, 0);
  }

  if (t == 2) {  // V transposed as [d][l'] (compacted columns)
#pragma unroll
    for (int et = 0; et < 4; et++)
#pragma unroll
      for (int r = 0; r < 4; r++)
        tile[et * 16 + row16][w * 16 + g * 4 + r] = bf16r(acc[et][r]);
  } else {
#pragma unroll
    for (int et = 0; et < 4; et++)
#pragma unroll
      for (int r = 0; r < 4; r++)
        tile[w * 16 + g * 4 + r][et * 16 + row16] = bf16r(acc[et][r]);
  }
  __syncthreads();

  size_t nh = (size_t)(n * NH + h);
#pragma unroll
  for (int i = tid; i < 512; i += 256) {
    int rr = i >> 3, cc = i & 7;
    short8 v = *(const short8*)&tile[rr][cc * 8];
    if (t == 2)
      *(short8*)(Vt + (nh * HD + rr) * LSEQ + lt * 64 + cc * 8) = v;
    else
      *(short8*)(Kp + (nh * LSEQ + lt * 64 + rr) * HD + cc * 8) = v;
  }
}

// ------------------------------------------------------------ flash attention
// qtile=256, 512 threads = 8 waves x 32 q-rows (2 halves: K/V fragments feed
// 2x MFMA = half the LDS-reads/FLOP); KVBLK=128 (half the barriers); 3-DEEP
// COUNTED-VMCNT pipeline: iter kt stages tile kt+2 (4 stage16/wave), barrier
// waits vmcnt(4) so kt+2's stages stay in flight -- never a full drain in
// steady state. fbias lives in LDS (only in-loop VMEM = the 4 stages).
// Q projection fused in the prologue; fixed-max softmax p=exp2(s-32);
// chunk-XOR swizzle; bias as MFMA C-init; XCD swizzle.
// LDS: 3 bufs x (K16K|V16K) = 96K | P 8x4K = 32K | fbias 8K -> 139264 B,
// 1 block/CU. Blocks 256..383: Wo->bf16 conversion tail.
__global__ __launch_bounds__(512, 1) void attn_kernel(
    const float* __restrict__ query, const short* __restrict__ Wqb,
    const short* __restrict__ Kp, const short* __restrict__ Vt,
    const float* __restrict__ fbias, const int* __restrict__ meta,
    short* __restrict__ aout, const float* __restrict__ Wo,
    short* __restrict__ Wob) {
  __shared__ __align__(16) char smem[139264];

  int idx = blockIdx.x;
  int tid = threadIdx.x;
  if (idx >= NBATCH * NH * (LSEQ / 256)) {       // Wo conversion tail blocks
    int i = (idx - NBATCH * NH * (LSEQ / 256)) * 512 + tid;
    float4 v = ((const float4*)Wo)[i];
    short4v r;
    r[0]=bf16r(v.x); r[1]=bf16r(v.y); r[2]=bf16r(v.z); r[3]=bf16r(v.w);
    ((short4v*)Wob)[i] = r;
    return;
  }
  // idx = n*64 + qt*8 + h  -> XCD (idx%8) == h; K/V of one head stay on 1 XCD
  int h = idx & 7;
  int qt = (idx >> 3) & 7;
  int n = idx >> 6;
  int lane = tid & 63, w = tid >> 6;            // w in [0,8)
  int q0 = lane & 15, g = lane >> 4;
  int xr = q0 & 7;
  int nkt = (meta[n] + 1) >> 1;                 // 128-key tiles

  size_t nh = (size_t)(n * NH + h);

  const char* Ksrc = (const char*)(Kp + nh * (size_t)LSEQ * HD);  // [l'][d] 128B rows
  const char* Vsrc = (const char*)(Vt + nh * (size_t)HD * LSEQ);  // [d][L'] 4KB rows

  // staging: K tile 128r x 128B = 1024 chunks; V tile 64r x 256B = 1024 chunks
  // (16B each), 2 K + 2 V per thread. Source chunk-in-row ^= row&7 (within
  // 8-chunk halves for V) so linear LDS + XOR'd read are conflict-free.
  int ksoff[2], vsoff[2], ldo[2];
#pragma unroll
  for (int j = 0; j < 2; j++) {
    int c = j * 512 + w * 64 + lane;
    int rK = c >> 3, cwK = (c & 7) ^ (rK & 7);
    ksoff[j] = rK * 128 + cwK * 16;
    int rV = c >> 4, cwV = c & 15;
    int sub = (cwV & 7) ^ (rV & 7);
    vsoff[j] = rV * (LSEQ * 2) + ((cwV & 8) + sub) * 16;
    ldo[j] = (j * 512 + w * 64) * 16;           // wave-uniform (+ lane*16 by HW)
  }

  int kfragb = q0 * 128 + ((g ^ xr) << 4);      // + h2*8192 + ks*2048; ^64 half
  int vfragb = q0 * 256 + ((g ^ xr) << 4);      // + h2*128  + dt*4096; ^64 half
  // P region at 98304: per wave 32 rows x 128B; q-half1 at +2048
  int pbase = 98304 + w * 4096 + q0 * 128;
  char* pw_[4];
#pragma unroll
  for (int ks = 0; ks < 4; ks++)
    pw_[ks] = smem + pbase + ((ks * 32 + g * 8) ^ (xr << 4));
  const char* pr0 = smem + pbase + ((g * 16) ^ (xr << 4));
  const char* pr1 = smem + pbase + ((64 + g * 16) ^ (xr << 4));

  // ---- prologue staging part 1: fbias (1 VMEM/wave) + tile 0 (4 VMEM/wave)
  stage16(fbias + n * LSEQ + w * 256 + lane * 4, smem + 131072 + w * 1024);
#pragma unroll
  for (int j = 0; j < 2; j++) stage16(Ksrc + ksoff[j], smem + ldo[j]);
#pragma unroll
  for (int j = 0; j < 2; j++) stage16(Vsrc + vsoff[j], smem + 16384 + ldo[j]);

  // ---- fused Q projection (validated): D[e][q] = Wq x^T -> lane holds
  // Q[q0][et*16+g*4+r] -> cvt_pk -> ds_write_b64 into this wave's P region.
  // Its VGPR loads force the compiler to drain fbias+tile0 (harmless: hidden
  // under this compute); tile 1 is issued AFTER so it stays in flight.
  {
    short8 wf0[4], wf1[4];
#pragma unroll
    for (int et = 0; et < 4; et++) {
      wf0[et] = ld8(Wqb + (et * 16 + q0) * HD + g * 8);
      wf1[et] = ld8(Wqb + (et * 16 + q0) * HD + 32 + g * 8);
    }
    int zq = meta[4 + n];
#pragma unroll
    for (int hh = 0; hh < 2; hh++) {
      const float* xrow = query +
          ((size_t)(n * LSEQ + qt * 256 + w * 32 + hh * 16 + q0)) * EMB +
          h * HD + g * 8;
      short8 xa0 = cvt8(xrow);
      short8 xa1 = cvt8(xrow + 32);
#pragma unroll
      for (int et = 0; et < 4; et++) {
        f32x4 tq = (f32x4){0.f, 0.f, 0.f, 0.f};
        tq = __builtin_amdgcn_mfma_f32_16x16x32_bf16(wf0[et], xa0, tq, 0, 0, 0);
        tq = __builtin_amdgcn_mfma_f32_16x16x32_bf16(wf1[et], xa1, tq, 0, 0, 0);
        if (zq) tq = (f32x4){0.f, 0.f, 0.f, 0.f};
        *(int2*)(smem + pbase + hh * 2048 + ((et * 32 + g * 8) ^ (xr << 4))) =
            make_int2((int)cvtpk(tq[0], tq[1]), (int)cvtpk(tq[2], tq[3]));
      }
    }
  }
  asm volatile("s_waitcnt lgkmcnt(0)" ::: "memory");
  short8 bq00 = *(const short8*)pr0;            // half 0
  short8 bq01 = *(const short8*)pr1;
  short8 bq10 = *(const short8*)(pr0 + 2048);   // half 1
  short8 bq11 = *(const short8*)(pr1 + 2048);

  // ---- prologue staging part 2: tile 1 -> buf1 (4 VMEM/wave, stays in flight)
  if (nkt > 1) {
#pragma unroll
    for (int j = 0; j < 2; j++) stage16(Ksrc + 16384 + ksoff[j], smem + 32768 + ldo[j]);
#pragma unroll
    for (int j = 0; j < 2; j++) stage16(Vsrc + 256 + vsoff[j], smem + 32768 + 16384 + ldo[j]);
  }

  f32x4 acc0[4], acc1[4];
#pragma unroll
  for (int dt = 0; dt < 4; dt++) {
    acc0[dt] = (f32x4){0.f, 0.f, 0.f, 0.f};
    acc1[dt] = (f32x4){0.f, 0.f, 0.f, 0.f};
  }
  float l0 = 0.f, l1 = 0.f;

  // tile 0 ready (tile 1's 4 stages may stay in flight)
  if (nkt > 1)
    asm volatile("s_waitcnt vmcnt(4)" ::: "memory");
  else
    asm volatile("s_waitcnt vmcnt(0)" ::: "memory");
  __builtin_amdgcn_sched_barrier(0);
  __builtin_amdgcn_s_barrier();

  int cb = 0, sb = 2;                           // compute buf, stage buf
  for (int kt = 0; kt < nkt; kt++) {
    int bufo = cb * 32768;
    if (kt + 2 < nkt) {                         // stage tile kt+2 -> buf sb
      int sbo = sb * 32768;
      const char* Kn = Ksrc + (size_t)(kt + 2) * 16384;
      const char* Vn = Vsrc + (size_t)(kt + 2) * 256;
#pragma unroll
      for (int j = 0; j < 2; j++) stage16(Kn + ksoff[j], smem + sbo + ldo[j]);
#pragma unroll
      for (int j = 0; j < 2; j++) stage16(Vn + vsoff[j], smem + sbo + 16384 + ldo[j]);
    }

#pragma unroll
    for (int h2 = 0; h2 < 2; h2++) {
      f32x4 fbv[4];
#pragma unroll
      for (int ks = 0; ks < 4; ks++)
        fbv[ks] = *(const f32x4*)(smem + 131072 +
                                  (kt * 128 + h2 * 64 + ks * 16 + g * 4) * 4);

      // ---- S^T = K Q^T for both q-halves; bias pre-loaded as MFMA C-init
      int kb_l = bufo + h2 * 8192 + kfragb;
      f32x4 s0[4], s1[4];
      __builtin_amdgcn_s_setprio(1);
#pragma unroll
      for (int ks = 0; ks < 4; ks++) {
        short8 k0 = *(const short8*)(smem + (kb_l + ks * 2048));
        short8 k1 = *(const short8*)(smem + ((kb_l + ks * 2048) ^ 64));
        f32x4 t0 = __builtin_amdgcn_mfma_f32_16x16x32_bf16(k0, bq00, fbv[ks], 0, 0, 0);
        s0[ks]   = __builtin_amdgcn_mfma_f32_16x16x32_bf16(k1, bq01, t0, 0, 0, 0);
        f32x4 t1 = __builtin_amdgcn_mfma_f32_16x16x32_bf16(k0, bq10, fbv[ks], 0, 0, 0);
        s1[ks]   = __builtin_amdgcn_mfma_f32_16x16x32_bf16(k1, bq11, t1, 0, 0, 0);
      }
      __builtin_amdgcn_s_setprio(0);

      // ---- p = exp2(s - 32) (fixed max), pack, write P (half1 at +2048)
      float ps0 = 0.f, ps1 = 0.f;
#pragma unroll
      for (int ks = 0; ks < 4; ks++) {
        float p0 = exp2v(s0[ks][0] - 32.f), p1 = exp2v(s0[ks][1] - 32.f);
        float p2 = exp2v(s0[ks][2] - 32.f), p3 = exp2v(s0[ks][3] - 32.f);
        ps0 += (p0 + p1) + (p2 + p3);
        *(int2*)pw_[ks] = make_int2((int)cvtpk(p0, p1), (int)cvtpk(p2, p3));
        float q1 = exp2v(s1[ks][0] - 32.f), q2 = exp2v(s1[ks][1] - 32.f);
        float q3 = exp2v(s1[ks][2] - 32.f), q4 = exp2v(s1[ks][3] - 32.f);
        ps1 += (q1 + q2) + (q3 + q4);
        *(int2*)(pw_[ks] + 2048) = make_int2((int)cvtpk(q1, q2), (int)cvtpk(q3, q4));
      }
      l0 += ps0; l1 += ps1;

      asm volatile("s_waitcnt lgkmcnt(0)" ::: "memory");

      // ---- O += P V (V fragments shared by both q-halves)
      short8 ap00 = *(const short8*)pr0;
      short8 ap01 = *(const short8*)pr1;
      short8 ap10 = *(const short8*)(pr0 + 2048);
      short8 ap11 = *(const short8*)(pr1 + 2048);
      int vb_l = bufo + 16384 + vfragb + h2 * 128;
      __builtin_amdgcn_s_setprio(1);
#pragma unroll
      for (int dt = 0; dt < 4; dt++) {
        short8 v0 = *(const short8*)(smem + (vb_l + dt * 4096));
        short8 v1 = *(const short8*)(smem + ((vb_l + dt * 4096) ^ 64));
        acc0[dt] = __builtin_amdgcn_mfma_f32_16x16x32_bf16(ap00, v0, acc0[dt], 0, 0, 0);
        acc0[dt] = __builtin_amdgcn_mfma_f32_16x16x32_bf16(ap01, v1, acc0[dt], 0, 0, 0);
        acc1[dt] = __builtin_amdgcn_mfma_f32_16x16x32_bf16(ap10, v0, acc1[dt], 0, 0, 0);
        acc1[dt] = __builtin_amdgcn_mfma_f32_16x16x32_bf16(ap11, v1, acc1[dt], 0, 0, 0);
      }
      __builtin_amdgcn_s_setprio(0);
    }

    // ---- counted-vmcnt barrier: tile kt+1's 4 stages (issued iter kt-1)
    // must be complete; tile kt+2's 4 (issued this iter) stay in flight.
    if (kt + 2 < nkt)
      asm volatile("s_waitcnt vmcnt(4)" ::: "memory");
    else
      asm volatile("s_waitcnt vmcnt(0)" ::: "memory");
    __builtin_amdgcn_sched_barrier(0);
    __builtin_amdgcn_s_barrier();

    cb = (cb == 2) ? 0 : cb + 1;
    sb = (sb == 2) ? 0 : sb + 1;
  }

  // ---- epilogue
  l0 += __shfl_xor(l0, 16);  l0 += __shfl_xor(l0, 32);
  l1 += __shfl_xor(l1, 16);  l1 += __shfl_xor(l1, 32);
  float li0 = l0 > 0.f ? 1.f / l0 : 0.f;
  float li1 = l1 > 0.f ? 1.f / l1 : 0.f;
  int lb = lane & 48;
  float w0[4], w1[4];
#pragma unroll
  for (int r = 0; r < 4; r++) {
    w0[r] = __shfl(li0, lb + g * 4 + r);
    w1[r] = __shfl(li1, lb + g * 4 + r);
  }
  int qrow = qt * 256 + w * 32;
#pragma unroll
  for (int r = 0; r < 4; r++) {
    size_t o0 = ((size_t)(n * LSEQ + qrow + g * 4 + r)) * EMB + h * HD;
    size_t o1 = ((size_t)(n * LSEQ + qrow + 16 + g * 4 + r)) * EMB + h * HD;
#pragma unroll
    for (int dt = 0; dt < 4; dt++) {
      aout[o0 + dt * 16 + q0] = bf16r(acc0[dt][r] * w0[r]);
      aout[o1 + dt * 16 + q0] = bf16r(acc1[dt][r] * w1[r]);
    }
  }
}

// --------------------------------------------------- final projection + bias
// 512 threads = 8 waves x 32 rows (2 hh): grid (32,8) = 1 block/CU but now
// 8 waves/CU (was 4: grid-limited TLP starvation for a latency-sensitive
// direct-global GEMM). B-fragments duplicated across wave pairs -> L1-hot.
__global__ __launch_bounds__(512) void outproj_kernel(
    const short* __restrict__ aout, const short* __restrict__ Wob,
    const float* __restrict__ bo, float* __restrict__ out) {
  int mt = blockIdx.x, nt = blockIdx.y;
  int tid = threadIdx.x, lane = tid & 63, w = tid >> 6;
  int row16 = lane & 15, g = lane >> 4;
  int mrow = mt * 256 + w * 32;

  f32x4 acc[2][4];   // [row-half][et]
#pragma unroll
  for (int hh = 0; hh < 2; hh++)
#pragma unroll
    for (int et = 0; et < 4; et++) acc[hh][et] = (f32x4){0.f, 0.f, 0.f, 0.f};

  for (int kc = 0; kc < 16; kc++) {
    short8 a[2];
#pragma unroll
    for (int hh = 0; hh < 2; hh++)
      a[hh] = ld8(aout + (size_t)(mrow + hh * 16 + row16) * EMB + kc * 32 + g * 8);
#pragma unroll
    for (int et = 0; et < 4; et++) {
      short8 bw = ld8(Wob + (size_t)(nt * 64 + et * 16 + row16) * EMB + kc * 32 + g * 8);
#pragma unroll
      for (int hh = 0; hh < 2; hh++)
        acc[hh][et] = __builtin_amdgcn_mfma_f32_16x16x32_bf16(a[hh], bw, acc[hh][et], 0, 0, 0);
    }
  }
#pragma unroll
  for (int et = 0; et < 4; et++) {
    int e = nt * 64 + et * 16 + row16;
    float bias = bo[e];
#pragma unroll
    for (int hh = 0; hh < 2; hh++)
#pragma unroll
      for (int r = 0; r < 4; r++)
        out[(size_t)(mrow + hh * 16 + g * 4 + r) * EMB + e] = acc[hh][et][r] + bias;
  }
}

extern "C" void kernel_launch(void* const* d_in, const int* in_sizes, int n_in,
                              void* d_out, int out_size, void* d_ws, size_t ws_size,
                              hipStream_t stream) {
  const float* values = (const float*)d_in[0];
  const float* keys   = (const float*)d_in[1];
  const float* query  = (const float*)d_in[2];
  const int*   mask   = (const int*)d_in[3];
  const float* Wv     = (const float*)d_in[4];
  const float* Wk     = (const float*)d_in[5];
  const float* Wq     = (const float*)d_in[6];
  const float* Wo     = (const float*)d_in[7];
  const float* bo     = (const float*)d_in[8];
  float* out = (float*)d_out;

  // Kp scratch in d_out (8 MB, overwritten by outproj last; stream-ordered)
  short* Kp = (short*)d_out;
  char* ws = (char*)d_ws;
  short* Vt    = (short*)(ws);                              //  8 MB
  short* aout  = (short*)(ws + (8u << 20));                 //  8 MB
  short* Wob   = (short*)(ws + (16u << 20));                // 0.5 MB
  float* fbias = (float*)(ws + (16u << 20) + (512u << 10)); // 32 KB (compacted)
  int*   kidx  = (int*)  (ws + (16u << 20) + (544u << 10)); // 32 KB
  int*   meta  = (int*)  (ws + (16u << 20) + (576u << 10)); // 32 B
  short* Wqb   = (short*)(ws + (16u << 20) + (577u << 10)); // 8 KB
  short* Wkb   = (short*)(ws + (16u << 20) + (585u << 10)); // 8 KB
  short* Wvb   = (short*)(ws + (16u << 20) + (593u << 10)); // 8 KB

  prep_kernel<<<16, 256, 0, stream>>>(mask, fbias, kidx, meta,
                                      Wq, Wk, Wv, Wqb, Wkb, Wvb);
  proj_kernel<<<dim3(NBATCH * NH * (LSEQ / 64), 2), 256, 0, stream>>>(
      keys, values, Wkb, Wvb, kidx, meta, Kp, Vt);
  attn_kernel<<<NBATCH * NH * (LSEQ / 256) + 128, 512, 0, stream>>>(
      query, Wqb, Kp, Vt, fbias, meta, aout, Wo, Wob);
  outproj_kernel<<<dim3((NBATCH * LSEQ) / 256, EMB / 64), 512, 0, stream>>>(
      aout, Wob, bo, out);
}

// Round 25
// 75.162 us; speedup vs baseline: 1.0422x; 1.0422x over previous
//
#include <hip/hip_runtime.h>

#define LSEQ 2048
#define EMB  512
#define NH   8
#define HD   64
#define NBATCH 4
// 1/sqrt(512) * log2(e): folded into Wq at prep; softmax runs in exp2 domain
#define QSCALE (0.044194173824159216f * 1.4426950408889634f)

using short8  = __attribute__((ext_vector_type(8))) short;
using short4v = __attribute__((ext_vector_type(4))) short;
using f32x4   = __attribute__((ext_vector_type(4))) float;

__device__ __forceinline__ short bf16r(float f) {
  union { float f; unsigned u; } x; x.f = f;
  unsigned r = x.u + 0x7FFFu + ((x.u >> 16) & 1u);
  return (short)(r >> 16);
}

__device__ __forceinline__ float exp2v(float x) {
  float r;
  asm("v_exp_f32 %0, %1" : "=v"(r) : "v"(x));   // D = 2^S0
  return r;
}

// pack two f32 -> two bf16 in one dword (lo -> [15:0], hi -> [31:16]); RNE
__device__ __forceinline__ unsigned cvtpk(float lo, float hi) {
  unsigned r;
  asm("v_cvt_pk_bf16_f32 %0, %1, %2" : "=v"(r) : "v"(lo), "v"(hi));
  return r;
}

// async global->LDS, 16B per lane; lds dest is wave-uniform (HW adds lane*16)
__device__ __forceinline__ void stage16(const void* g, void* l) {
  __builtin_amdgcn_global_load_lds(
      (const __attribute__((address_space(1))) unsigned int*)g,
      (__attribute__((address_space(3))) unsigned int*)l, 16, 0, 0);
}

__device__ __forceinline__ short8 cvt8(const float* __restrict__ p) {
  float4 a = ((const float4*)p)[0];
  float4 b = ((const float4*)p)[1];
  short8 r;
  r[0]=bf16r(a.x); r[1]=bf16r(a.y); r[2]=bf16r(a.z); r[3]=bf16r(a.w);
  r[4]=bf16r(b.x); r[5]=bf16r(b.y); r[6]=bf16r(b.z); r[7]=bf16r(b.w);
  return r;
}

__device__ __forceinline__ short8 ld8(const short* __restrict__ p) {
  return *(const short8*)p;
}

// ---- prep (16 blocks): mask compaction (0..3) | Wq*QSCALE,Wk,Wv->bf16 (4..15)
__global__ __launch_bounds__(256) void prep_kernel(
    const int* __restrict__ mask, float* __restrict__ fbias,
    int* __restrict__ kidx, int* __restrict__ meta,
    const float* __restrict__ Wq, const float* __restrict__ Wk,
    const float* __restrict__ Wv, short* __restrict__ Wqb,
    short* __restrict__ Wkb, short* __restrict__ Wvb) {
  __shared__ int ssum[256];
  int b = blockIdx.x;
  int tid = threadIdx.x;
  if (b < 4) {
    int n = b;
    int base = n * LSEQ;
    int loc[8], c = 0;
#pragma unroll
    for (int j = 0; j < 8; j++) { loc[j] = mask[base + tid * 8 + j] != 0; c += loc[j]; }
    ssum[tid] = c;
    __syncthreads();
    for (int off = 1; off < 256; off <<= 1) {
      int v = (tid >= off) ? ssum[tid - off] : 0;
      __syncthreads();
      ssum[tid] += v;
      __syncthreads();
    }
    int total = ssum[255];
    int excl = ssum[tid] - c;
    int qz = (total == 0);
#pragma unroll
    for (int j = 0; j < 8; j++) {
      int i = tid * 8 + j;
      kidx[base + i] = qz ? i : 0;
      fbias[base + i] = (qz || i < total) ? 0.f : -1e30f;
    }
    __syncthreads();
    if (!qz) {
      int pos = excl;
#pragma unroll
      for (int j = 0; j < 8; j++)
        if (loc[j]) { kidx[base + pos] = tid * 8 + j; pos++; }
    }
    if (tid == 0) {
      meta[n] = qz ? (LSEQ / 64) : ((total + 63) >> 6);
      meta[4 + n] = qz;
    }
  } else {
    int t = (b - 4) >> 2;                      // 0=Wq 1=Wk 2=Wv
    int i = ((b - 4) & 3) * 256 + tid;         // 1024 float4 per 64x64 W
    const float* W = (t == 0) ? Wq : (t == 1) ? Wk : Wv;
    short* O = (t == 0) ? Wqb : (t == 1) ? Wkb : Wvb;
    float sc = (t == 0) ? QSCALE : 1.f;
    float4 v = ((const float4*)W)[i];
    short4v r;
    r[0]=bf16r(v.x*sc); r[1]=bf16r(v.y*sc); r[2]=bf16r(v.z*sc); r[3]=bf16r(v.w*sc);
    ((short4v*)O)[i] = r;
  }
}

// --------------------------------------------- K/V projections (Q is in attn)
// K/V rows gathered through kidx (compacted keys), written up to the
// EVEN-rounded tile count ((meta+1)&~1)*64 rows; pad rows hold deterministic
// finite data (kidx=0, fbias=-1e30), never stale memory.
__global__ __launch_bounds__(256) void proj_kernel(
    const float* __restrict__ keys, const float* __restrict__ values,
    const short* __restrict__ Wkb, const short* __restrict__ Wvb,
    const int* __restrict__ kidx, const int* __restrict__ meta,
    short* __restrict__ Kp, short* __restrict__ Vt) {
  __shared__ short tile[64][72];                 // +8 pad
  int t = blockIdx.y + 1;                        // 1=K, 2=V
  const float* x = (t == 1) ? keys : values;
  const short* W = (t == 1) ? Wkb  : Wvb;
  int idx = blockIdx.x;
  int lt = idx & 31, h = (idx >> 5) & 7, n = idx >> 8;
  int tid = threadIdx.x, lane = tid & 63, w = tid >> 6;
  int row16 = lane & 15, g = lane >> 4;
  int lbase = lt * 64 + w * 16;

  if (lbase >= ((meta[n] + 1) & ~1) * 64) return;   // pad to even 64-tiles
  int gidx = kidx[n * LSEQ + lbase + row16];
  const float* xr = x + ((size_t)(n * LSEQ + gidx)) * EMB + h * HD + g * 8;
  short8 a0 = cvt8(xr);
  short8 a1 = cvt8(xr + 32);

  f32x4 acc[4];
#pragma unroll
  for (int et = 0; et < 4; et++) acc[et] = (f32x4){0.f, 0.f, 0.f, 0.f};
#pragma unroll
  for (int et = 0; et < 4; et++) {
    const short* wr = W + (size_t)(et * 16 + row16) * HD + g * 8;
    short8 b0 = ld8(wr);
    short8 b1 = ld8(wr + 32);
    acc[et] = __builtin_amdgcn_mfma_f32_16x16x32_bf16(a0, b0, acc[et], 0, 0, 0);
    acc[et] = __builtin_amdgcn_mfma_f32_16x16x32_bf16(a1, b1, acc[et], 0, 0, 0);
  }

  if (t == 2) {  // V transposed as [d][l'] (compacted columns)
#pragma unroll
    for (int et = 0; et < 4; et++)
#pragma unroll
      for (int r = 0; r < 4; r++)
        tile[et * 16 + row16][w * 16 + g * 4 + r] = bf16r(acc[et][r]);
  } else {
#pragma unroll
    for (int et = 0; et < 4; et++)
#pragma unroll
      for (int r = 0; r < 4; r++)
        tile[w * 16 + g * 4 + r][et * 16 + row16] = bf16r(acc[et][r]);
  }
  __syncthreads();

  size_t nh = (size_t)(n * NH + h);
#pragma unroll
  for (int i = tid; i < 512; i += 256) {
    int rr = i >> 3, cc = i & 7;
    short8 v = *(const short8*)&tile[rr][cc * 8];
    if (t == 2)
      *(short8*)(Vt + (nh * HD + rr) * LSEQ + lt * 64 + cc * 8) = v;
    else
      *(short8*)(Kp + (nh * LSEQ + lt * 64 + rr) * HD + cc * 8) = v;
  }
}

// ------------------------------------------------------------ flash attention
// qtile=256, 512 threads = 8 waves x 32 q-rows (2 halves: K/V fragments feed
// 2x MFMA = half the LDS-reads/FLOP); KVBLK=128 (half the barriers); 3-DEEP
// COUNTED-VMCNT pipeline: iter kt stages tile kt+2 (4 stage16/wave), barrier
// waits vmcnt(4) so kt+2's stages stay in flight -- never a full drain in
// steady state. fbias lives in LDS (only in-loop VMEM = the 4 stages).
// Q projection fused in the prologue; fixed-max softmax p=exp2(s-32);
// chunk-XOR swizzle; bias as MFMA C-init; XCD swizzle.
// LDS: 3 bufs x (K16K|V16K) = 96K | P 8x4K = 32K | fbias 8K -> 139264 B,
// 1 block/CU. Blocks 256..383: Wo->bf16 conversion tail.
__global__ __launch_bounds__(512, 1) void attn_kernel(
    const float* __restrict__ query, const short* __restrict__ Wqb,
    const short* __restrict__ Kp, const short* __restrict__ Vt,
    const float* __restrict__ fbias, const int* __restrict__ meta,
    short* __restrict__ aout, const float* __restrict__ Wo,
    short* __restrict__ Wob) {
  __shared__ __align__(16) char smem[139264];

  int idx = blockIdx.x;
  int tid = threadIdx.x;
  if (idx >= NBATCH * NH * (LSEQ / 256)) {       // Wo conversion tail blocks
    int i = (idx - NBATCH * NH * (LSEQ / 256)) * 512 + tid;
    float4 v = ((const float4*)Wo)[i];
    short4v r;
    r[0]=bf16r(v.x); r[1]=bf16r(v.y); r[2]=bf16r(v.z); r[3]=bf16r(v.w);
    ((short4v*)Wob)[i] = r;
    return;
  }
  // idx = n*64 + qt*8 + h  -> XCD (idx%8) == h; K/V of one head stay on 1 XCD
  int h = idx & 7;
  int qt = (idx >> 3) & 7;
  int n = idx >> 6;
  int lane = tid & 63, w = tid >> 6;            // w in [0,8)
  int q0 = lane & 15, g = lane >> 4;
  int xr = q0 & 7;
  int nkt = (meta[n] + 1) >> 1;                 // 128-key tiles

  size_t nh = (size_t)(n * NH + h);

  const char* Ksrc = (const char*)(Kp + nh * (size_t)LSEQ * HD);  // [l'][d] 128B rows
  const char* Vsrc = (const char*)(Vt + nh * (size_t)HD * LSEQ);  // [d][L'] 4KB rows

  // staging: K tile 128r x 128B = 1024 chunks; V tile 64r x 256B = 1024 chunks
  // (16B each), 2 K + 2 V per thread. Source chunk-in-row ^= row&7 (within
  // 8-chunk halves for V) so linear LDS + XOR'd read are conflict-free.
  int ksoff[2], vsoff[2], ldo[2];
#pragma unroll
  for (int j = 0; j < 2; j++) {
    int c = j * 512 + w * 64 + lane;
    int rK = c >> 3, cwK = (c & 7) ^ (rK & 7);
    ksoff[j] = rK * 128 + cwK * 16;
    int rV = c >> 4, cwV = c & 15;
    int sub = (cwV & 7) ^ (rV & 7);
    vsoff[j] = rV * (LSEQ * 2) + ((cwV & 8) + sub) * 16;
    ldo[j] = (j * 512 + w * 64) * 16;           // wave-uniform (+ lane*16 by HW)
  }

  int kfragb = q0 * 128 + ((g ^ xr) << 4);      // + h2*8192 + ks*2048; ^64 half
  int vfragb = q0 * 256 + ((g ^ xr) << 4);      // + h2*128  + dt*4096; ^64 half
  // P region at 98304: per wave 32 rows x 128B; q-half1 at +2048
  int pbase = 98304 + w * 4096 + q0 * 128;
  char* pw_[4];
#pragma unroll
  for (int ks = 0; ks < 4; ks++)
    pw_[ks] = smem + pbase + ((ks * 32 + g * 8) ^ (xr << 4));
  const char* pr0 = smem + pbase + ((g * 16) ^ (xr << 4));
  const char* pr1 = smem + pbase + ((64 + g * 16) ^ (xr << 4));

  // ---- prologue staging part 1: fbias (1 VMEM/wave) + tile 0 (4 VMEM/wave)
  stage16(fbias + n * LSEQ + w * 256 + lane * 4, smem + 131072 + w * 1024);
#pragma unroll
  for (int j = 0; j < 2; j++) stage16(Ksrc + ksoff[j], smem + ldo[j]);
#pragma unroll
  for (int j = 0; j < 2; j++) stage16(Vsrc + vsoff[j], smem + 16384 + ldo[j]);

  // ---- fused Q projection (validated): D[e][q] = Wq x^T -> lane holds
  // Q[q0][et*16+g*4+r] -> cvt_pk -> ds_write_b64 into this wave's P region.
  // Its VGPR loads force the compiler to drain fbias+tile0 (harmless: hidden
  // under this compute); tile 1 is issued AFTER so it stays in flight.
  {
    short8 wf0[4], wf1[4];
#pragma unroll
    for (int et = 0; et < 4; et++) {
      wf0[et] = ld8(Wqb + (et * 16 + q0) * HD + g * 8);
      wf1[et] = ld8(Wqb + (et * 16 + q0) * HD + 32 + g * 8);
    }
    int zq = meta[4 + n];
#pragma unroll
    for (int hh = 0; hh < 2; hh++) {
      const float* xrow = query +
          ((size_t)(n * LSEQ + qt * 256 + w * 32 + hh * 16 + q0)) * EMB +
          h * HD + g * 8;
      short8 xa0 = cvt8(xrow);
      short8 xa1 = cvt8(xrow + 32);
#pragma unroll
      for (int et = 0; et < 4; et++) {
        f32x4 tq = (f32x4){0.f, 0.f, 0.f, 0.f};
        tq = __builtin_amdgcn_mfma_f32_16x16x32_bf16(wf0[et], xa0, tq, 0, 0, 0);
        tq = __builtin_amdgcn_mfma_f32_16x16x32_bf16(wf1[et], xa1, tq, 0, 0, 0);
        if (zq) tq = (f32x4){0.f, 0.f, 0.f, 0.f};
        *(int2*)(smem + pbase + hh * 2048 + ((et * 32 + g * 8) ^ (xr << 4))) =
            make_int2((int)cvtpk(tq[0], tq[1]), (int)cvtpk(tq[2], tq[3]));
      }
    }
  }
  asm volatile("s_waitcnt lgkmcnt(0)" ::: "memory");
  short8 bq00 = *(const short8*)pr0;            // half 0
  short8 bq01 = *(const short8*)pr1;
  short8 bq10 = *(const short8*)(pr0 + 2048);   // half 1
  short8 bq11 = *(const short8*)(pr1 + 2048);

  // ---- prologue staging part 2: tile 1 -> buf1 (4 VMEM/wave, stays in flight)
  if (nkt > 1) {
#pragma unroll
    for (int j = 0; j < 2; j++) stage16(Ksrc + 16384 + ksoff[j], smem + 32768 + ldo[j]);
#pragma unroll
    for (int j = 0; j < 2; j++) stage16(Vsrc + 256 + vsoff[j], smem + 32768 + 16384 + ldo[j]);
  }

  f32x4 acc0[4], acc1[4];
#pragma unroll
  for (int dt = 0; dt < 4; dt++) {
    acc0[dt] = (f32x4){0.f, 0.f, 0.f, 0.f};
    acc1[dt] = (f32x4){0.f, 0.f, 0.f, 0.f};
  }
  float l0 = 0.f, l1 = 0.f;

  // tile 0 ready (tile 1's 4 stages may stay in flight)
  if (nkt > 1)
    asm volatile("s_waitcnt vmcnt(4)" ::: "memory");
  else
    asm volatile("s_waitcnt vmcnt(0)" ::: "memory");
  __builtin_amdgcn_sched_barrier(0);
  __builtin_amdgcn_s_barrier();

  int cb = 0, sb = 2;                           // compute buf, stage buf
  for (int kt = 0; kt < nkt; kt++) {
    int bufo = cb * 32768;
    if (kt + 2 < nkt) {                         // stage tile kt+2 -> buf sb
      int sbo = sb * 32768;
      const char* Kn = Ksrc + (size_t)(kt + 2) * 16384;
      const char* Vn = Vsrc + (size_t)(kt + 2) * 256;
#pragma unroll
      for (int j = 0; j < 2; j++) stage16(Kn + ksoff[j], smem + sbo + ldo[j]);
#pragma unroll
      for (int j = 0; j < 2; j++) stage16(Vn + vsoff[j], smem + sbo + 16384 + ldo[j]);
    }

#pragma unroll
    for (int h2 = 0; h2 < 2; h2++) {
      f32x4 fbv[4];
#pragma unroll
      for (int ks = 0; ks < 4; ks++)
        fbv[ks] = *(const f32x4*)(smem + 131072 +
                                  (kt * 128 + h2 * 64 + ks * 16 + g * 4) * 4);

      // ---- S^T = K Q^T for both q-halves; bias pre-loaded as MFMA C-init
      int kb_l = bufo + h2 * 8192 + kfragb;
      f32x4 s0[4], s1[4];
      __builtin_amdgcn_s_setprio(1);
#pragma unroll
      for (int ks = 0; ks < 4; ks++) {
        short8 k0 = *(const short8*)(smem + (kb_l + ks * 2048));
        short8 k1 = *(const short8*)(smem + ((kb_l + ks * 2048) ^ 64));
        f32x4 t0 = __builtin_amdgcn_mfma_f32_16x16x32_bf16(k0, bq00, fbv[ks], 0, 0, 0);
        s0[ks]   = __builtin_amdgcn_mfma_f32_16x16x32_bf16(k1, bq01, t0, 0, 0, 0);
        f32x4 t1 = __builtin_amdgcn_mfma_f32_16x16x32_bf16(k0, bq10, fbv[ks], 0, 0, 0);
        s1[ks]   = __builtin_amdgcn_mfma_f32_16x16x32_bf16(k1, bq11, t1, 0, 0, 0);
      }
      __builtin_amdgcn_s_setprio(0);

      // ---- p = exp2(s - 32) (fixed max), pack, write P (half1 at +2048)
      float ps0 = 0.f, ps1 = 0.f;
#pragma unroll
      for (int ks = 0; ks < 4; ks++) {
        float p0 = exp2v(s0[ks][0] - 32.f), p1 = exp2v(s0[ks][1] - 32.f);
        float p2 = exp2v(s0[ks][2] - 32.f), p3 = exp2v(s0[ks][3] - 32.f);
        ps0 += (p0 + p1) + (p2 + p3);
        *(int2*)pw_[ks] = make_int2((int)cvtpk(p0, p1), (int)cvtpk(p2, p3));
        float q1 = exp2v(s1[ks][0] - 32.f), q2 = exp2v(s1[ks][1] - 32.f);
        float q3 = exp2v(s1[ks][2] - 32.f), q4 = exp2v(s1[ks][3] - 32.f);
        ps1 += (q1 + q2) + (q3 + q4);
        *(int2*)(pw_[ks] + 2048) = make_int2((int)cvtpk(q1, q2), (int)cvtpk(q3, q4));
      }
      l0 += ps0; l1 += ps1;

      asm volatile("s_waitcnt lgkmcnt(0)" ::: "memory");

      // ---- O += P V (V fragments shared by both q-halves)
      short8 ap00 = *(const short8*)pr0;
      short8 ap01 = *(const short8*)pr1;
      short8 ap10 = *(const short8*)(pr0 + 2048);
      short8 ap11 = *(const short8*)(pr1 + 2048);
      int vb_l = bufo + 16384 + vfragb + h2 * 128;
      __builtin_amdgcn_s_setprio(1);
#pragma unroll
      for (int dt = 0; dt < 4; dt++) {
        short8 v0 = *(const short8*)(smem + (vb_l + dt * 4096));
        short8 v1 = *(const short8*)(smem + ((vb_l + dt * 4096) ^ 64));
        acc0[dt] = __builtin_amdgcn_mfma_f32_16x16x32_bf16(ap00, v0, acc0[dt], 0, 0, 0);
        acc0[dt] = __builtin_amdgcn_mfma_f32_16x16x32_bf16(ap01, v1, acc0[dt], 0, 0, 0);
        acc1[dt] = __builtin_amdgcn_mfma_f32_16x16x32_bf16(ap10, v0, acc1[dt], 0, 0, 0);
        acc1[dt] = __builtin_amdgcn_mfma_f32_16x16x32_bf16(ap11, v1, acc1[dt], 0, 0, 0);
      }
      __builtin_amdgcn_s_setprio(0);
    }

    // ---- counted-vmcnt barrier: tile kt+1's 4 stages (issued iter kt-1)
    // must be complete; tile kt+2's 4 (issued this iter) stay in flight.
    if (kt + 2 < nkt)
      asm volatile("s_waitcnt vmcnt(4)" ::: "memory");
    else
      asm volatile("s_waitcnt vmcnt(0)" ::: "memory");
    __builtin_amdgcn_sched_barrier(0);
    __builtin_amdgcn_s_barrier();

    cb = (cb == 2) ? 0 : cb + 1;
    sb = (sb == 2) ? 0 : sb + 1;
  }

  // ---- epilogue
  l0 += __shfl_xor(l0, 16);  l0 += __shfl_xor(l0, 32);
  l1 += __shfl_xor(l1, 16);  l1 += __shfl_xor(l1, 32);
  float li0 = l0 > 0.f ? 1.f / l0 : 0.f;
  float li1 = l1 > 0.f ? 1.f / l1 : 0.f;
  int lb = lane & 48;
  float w0[4], w1[4];
#pragma unroll
  for (int r = 0; r < 4; r++) {
    w0[r] = __shfl(li0, lb + g * 4 + r);
    w1[r] = __shfl(li1, lb + g * 4 + r);
  }
  int qrow = qt * 256 + w * 32;
#pragma unroll
  for (int r = 0; r < 4; r++) {
    size_t o0 = ((size_t)(n * LSEQ + qrow + g * 4 + r)) * EMB + h * HD;
    size_t o1 = ((size_t)(n * LSEQ + qrow + 16 + g * 4 + r)) * EMB + h * HD;
#pragma unroll
    for (int dt = 0; dt < 4; dt++) {
      aout[o0 + dt * 16 + q0] = bf16r(acc0[dt][r] * w0[r]);
      aout[o1 + dt * 16 + q0] = bf16r(acc1[dt][r] * w1[r]);
    }
  }
}

// --------------------------------------------------- final projection + bias
// 256-row tiles: wave owns 64 rows (4 halves) -> every Wob fragment feeds 4
// MFMA. Grid (32, 8) = 1 block/CU. (512-thread variant measured SLOWER:
// B-reuse 4x beats the extra TLP.)
__global__ __launch_bounds__(256) void outproj_kernel(
    const short* __restrict__ aout, const short* __restrict__ Wob,
    const float* __restrict__ bo, float* __restrict__ out) {
  int mt = blockIdx.x, nt = blockIdx.y;
  int tid = threadIdx.x, lane = tid & 63, w = tid >> 6;
  int row16 = lane & 15, g = lane >> 4;
  int mrow = mt * 256 + w * 64;

  f32x4 acc[4][4];   // [row-half][et]
#pragma unroll
  for (int hh = 0; hh < 4; hh++)
#pragma unroll
    for (int et = 0; et < 4; et++) acc[hh][et] = (f32x4){0.f, 0.f, 0.f, 0.f};

  for (int kc = 0; kc < 16; kc++) {
    short8 a[4];
#pragma unroll
    for (int hh = 0; hh < 4; hh++)
      a[hh] = ld8(aout + (size_t)(mrow + hh * 16 + row16) * EMB + kc * 32 + g * 8);
#pragma unroll
    for (int et = 0; et < 4; et++) {
      short8 bw = ld8(Wob + (size_t)(nt * 64 + et * 16 + row16) * EMB + kc * 32 + g * 8);
#pragma unroll
      for (int hh = 0; hh < 4; hh++)
        acc[hh][et] = __builtin_amdgcn_mfma_f32_16x16x32_bf16(a[hh], bw, acc[hh][et], 0, 0, 0);
    }
  }
#pragma unroll
  for (int et = 0; et < 4; et++) {
    int e = nt * 64 + et * 16 + row16;
    float bias = bo[e];
#pragma unroll
    for (int hh = 0; hh < 4; hh++)
#pragma unroll
      for (int r = 0; r < 4; r++)
        out[(size_t)(mrow + hh * 16 + g * 4 + r) * EMB + e] = acc[hh][et][r] + bias;
  }
}

extern "C" void kernel_launch(void* const* d_in, const int* in_sizes, int n_in,
                              void* d_out, int out_size, void* d_ws, size_t ws_size,
                              hipStream_t stream) {
  const float* values = (const float*)d_in[0];
  const float* keys   = (const float*)d_in[1];
  const float* query  = (const float*)d_in[2];
  const int*   mask   = (const int*)d_in[3];
  const float* Wv     = (const float*)d_in[4];
  const float* Wk     = (const float*)d_in[5];
  const float* Wq     = (const float*)d_in[6];
  const float* Wo     = (const float*)d_in[7];
  const float* bo     = (const float*)d_in[8];
  float* out = (float*)d_out;

  // Kp scratch in d_out (8 MB, overwritten by outproj last; stream-ordered)
  short* Kp = (short*)d_out;
  char* ws = (char*)d_ws;
  short* Vt    = (short*)(ws);                              //  8 MB
  short* aout  = (short*)(ws + (8u << 20));                 //  8 MB
  short* Wob   = (short*)(ws + (16u << 20));                // 0.5 MB
  float* fbias = (float*)(ws + (16u << 20) + (512u << 10)); // 32 KB (compacted)
  int*   kidx  = (int*)  (ws + (16u << 20) + (544u << 10)); // 32 KB
  int*   meta  = (int*)  (ws + (16u << 20) + (576u << 10)); // 32 B
  short* Wqb   = (short*)(ws + (16u << 20) + (577u << 10)); // 8 KB
  short* Wkb   = (short*)(ws + (16u << 20) + (585u << 10)); // 8 KB
  short* Wvb   = (short*)(ws + (16u << 20) + (593u << 10)); // 8 KB

  prep_kernel<<<16, 256, 0, stream>>>(mask, fbias, kidx, meta,
                                      Wq, Wk, Wv, Wqb, Wkb, Wvb);
  proj_kernel<<<dim3(NBATCH * NH * (LSEQ / 64), 2), 256, 0, stream>>>(
      keys, values, Wkb, Wvb, kidx, meta, Kp, Vt);
  attn_kernel<<<NBATCH * NH * (LSEQ / 256) + 128, 512, 0, stream>>>(
      query, Wqb, Kp, Vt, fbias, meta, aout, Wo, Wob);
  outproj_kernel<<<dim3((NBATCH * LSEQ) / 256, EMB / 64), 256, 0, stream>>>(
      aout, Wob, bo, out);
}